// Round 2
// baseline (643.964 us; speedup 1.0000x reference)
//
#include <hip/hip_runtime.h>
#include <hip/hip_bf16.h>
#include <stdint.h>

// ---------------------------------------------------------------------------
// MHA: B=2, S=4096, D=512, H=8, dk=64.
// R11:
//  * flash: 1024-thr blocks (16 waves), 4-way key split (ks=wave>>2 handles
//    key groups 4i+ks), 32 iters x 32KB staged group-quads, double-buffered
//    64KB sKV. End combine reuses sKV as float scratch (union) + 6KB comb_l
//    => ~70KB LDS, 2 blocks/CU x 16 waves = 8 waves/SIMD (launch_bounds
//    (1024,8) locks VGPR<=64). Per-CU traffic identical to R10; only
//    resident-wave count doubles.
//  * proj3/proj_o: 128x128 tile (m97 geometry: 16 MFMA + 10 ds_read per
//    k-step per wave), BK=32 double-buffered global_load_lds staging,
//    XOR-swizzled fragment reads. Epilogues unchanged.
//  * cvt3+cvtw merged into one flat-grid kernel (one fewer launch).
// ---------------------------------------------------------------------------

typedef float  floatx4 __attribute__((ext_vector_type(4)));
typedef __bf16 bf16x8  __attribute__((ext_vector_type(8)));
typedef short  shortx4 __attribute__((ext_vector_type(4)));

#define MFMA16(a, b, c) __builtin_amdgcn_mfma_f32_16x16x32_bf16((a), (b), (c), 0, 0, 0)

// folded into Q projection: (1/sqrt(64)) * log2(e)  -> scores in log2 domain
#define QSCALE 0.1803368801111244f

__device__ __forceinline__ short f2bf(float f) {   // RNE
  union { float f; uint32_t u; } a; a.f = f;
  uint32_t u = a.u;
  u += 0x7fffu + ((u >> 16) & 1u);
  return (short)(u >> 16);
}

// async global->LDS, 16B per lane; lds dest = wave-uniform base + lane*16
__device__ __forceinline__ void stage16(const short* g, short* l) {
  __builtin_amdgcn_global_load_lds(
      (const __attribute__((address_space(1))) void*)g,
      (__attribute__((address_space(3))) void*)l, 16, 0, 0);
}

// ---------------------------------------------------------------------------
// fp32 -> bf16 for all 7 tensors in one flat grid.
// act: q,k,v (A4 float4-units each, A4 = 2^20); wts: Wq,Wk,Wv,Wo (W4 = 2^16).
// ---------------------------------------------------------------------------
__global__ __launch_bounds__(256) void cvt_all_kernel(
    const float* __restrict__ q, const float* __restrict__ k, const float* __restrict__ v,
    const float* __restrict__ Wq, const float* __restrict__ Wk,
    const float* __restrict__ Wv, const float* __restrict__ Wo,
    short* __restrict__ act, short* __restrict__ wts) {
  const int A4 = (2 * 4096 * 512) / 4;   // 1048576 = 2^20
  const int W4 = (512 * 512) / 4;        // 65536   = 2^16
  const int i = blockIdx.x * 256 + threadIdx.x;
  const float* in;
  short* out;
  int j;
  if (i < 3 * A4) {
    const int which = i >> 20;           // / A4
    j = i - which * A4;
    in = which == 0 ? q : which == 1 ? k : v;
    out = act + (size_t)which * (size_t)A4 * 4;
  } else {
    const int t = i - 3 * A4;
    const int which = t >> 16;           // / W4
    j = t - which * W4;
    in = which == 0 ? Wq : which == 1 ? Wk : which == 2 ? Wv : Wo;
    out = wts + (size_t)which * (size_t)W4 * 4;
  }
  float4 f = reinterpret_cast<const float4*>(in)[j];
  shortx4 s;
  s.x = f2bf(f.x); s.y = f2bf(f.y); s.z = f2bf(f.z); s.w = f2bf(f.w);
  reinterpret_cast<shortx4*>(out)[j] = s;
}

// ---------------------------------------------------------------------------
// Fused Q/K/V projection. blockIdx.z picks tensor. A[8192,512] x W[512,512]^T.
// 128x128 tile, BK=32, double-buffered LDS (global_load_lds, 1 barrier/iter).
// LDS layout: row-major [rows][32] with k-chunk XOR swizzle:
//   cell(row, q) stored at chunk q ^ ((row ^ (row>>2)) & 3)   (16B chunks)
// Staging pre-swizzles the GLOBAL source k-offset (LDS dest stays linear);
// fragment ds_read applies the same XOR (depends only on l15 — invariant in
// mt/nt/wave since those shift row by multiples of 4).
// Wave = 32 rows x 128 cols: 16 MFMA / 10 ds_read_b128 per k-step.
// Epilogues identical to R9/R10 (Q scaled log2-domain; K/V fragment-ordered).
// ---------------------------------------------------------------------------
__global__ __launch_bounds__(256) void proj3_kernel(
    const short* __restrict__ xq, const short* __restrict__ xk, const short* __restrict__ xv,
    const short* __restrict__ wq, const short* __restrict__ wk, const short* __restrict__ wv,
    const float* __restrict__ bq, const float* __restrict__ bk, const float* __restrict__ bv,
    short* __restrict__ Qh, short* __restrict__ KV) {
  const int which = blockIdx.z;
  const short* A = which == 0 ? xq : which == 1 ? xk : xv;
  const short* W = which == 0 ? wq : which == 1 ? wk : wv;
  const float* bias = which == 0 ? bq : which == 1 ? bk : bv;

  __shared__ __align__(16) short sA[2][4096];   // [128][32] swizzled
  __shared__ __align__(16) short sB[2][4096];   // [128][32] swizzled

  const int K = 512;
  const int tid = threadIdx.x;
  const int lane = tid & 63;
  const int wave = tid >> 6;
  const int l15 = lane & 15;
  const int quad = lane >> 4;
  const int tileM = blockIdx.x * 128;
  const int tileN = blockIdx.y * 128;

  // staging: thread t covers LDS 16B chunk (row = t>>2 [+64], chunk = t&3);
  // source k-chunk pre-swizzled so LDS holds cell(row, (t&3)^fr) at slot t&3.
  const int srow = tid >> 2;                       // 0..63
  const int fr = (srow ^ (srow >> 2)) & 3;         // same for srow+64
  const int sq = ((tid & 3) ^ fr) * 8;
  const short* As0 = A + (size_t)(tileM + srow) * K + sq;        // rows 0..63
  const short* As1 = As0 + (size_t)64 * K;                       // rows 64..127
  const short* Bs0 = W + (size_t)(tileN + srow) * K + sq;
  const short* Bs1 = Bs0 + (size_t)64 * K;
  const int ldw = wave * 512;                      // wave-uniform LDS slice (shorts)

  // fragment reads: swizzled chunk = quad ^ f(l15)
  const int fl = (l15 ^ (l15 >> 2)) & 3;
  const int qsw = (quad ^ fl) * 8;
  const int ra0 = (wave * 32 + l15) * 32 + qsw;    // A frag mt=0
  const int ra1 = ra0 + 512;                       // mt=1 (+16 rows)
  const int rb0 = l15 * 32 + qsw;                  // B frag (+ nt*512)

  floatx4 acc[2][8];
#pragma unroll
  for (int mt = 0; mt < 2; ++mt)
#pragma unroll
    for (int nt = 0; nt < 8; ++nt) acc[mt][nt] = (floatx4){0.f, 0.f, 0.f, 0.f};

  // prologue: stage k-slice 0 into buffer 0
  stage16(As0, &sA[0][ldw]);
  stage16(As1, &sA[0][2048 + ldw]);
  stage16(Bs0, &sB[0][ldw]);
  stage16(Bs1, &sB[0][2048 + ldw]);

#pragma unroll 2
  for (int t = 0; t < 16; ++t) {
    __syncthreads();                 // drains own stage vmcnt + block sync
    if (t != 15) {                   // stage next slice into other buffer
      const int kk = (t + 1) * 32;
      short* a_ld = &sA[(t + 1) & 1][ldw];
      short* b_ld = &sB[(t + 1) & 1][ldw];
      stage16(As0 + kk, a_ld);
      stage16(As1 + kk, a_ld + 2048);
      stage16(Bs0 + kk, b_ld);
      stage16(Bs1 + kk, b_ld + 2048);
    }
    const short* sa = sA[t & 1];
    const short* sb = sB[t & 1];
    bf16x8 a0 = *(const bf16x8*)&sa[ra0];
    bf16x8 a1 = *(const bf16x8*)&sa[ra1];
#pragma unroll
    for (int nt = 0; nt < 8; ++nt) {
      bf16x8 wf = *(const bf16x8*)&sb[rb0 + nt * 512];
      acc[0][nt] = MFMA16(a0, wf, acc[0][nt]);
      acc[1][nt] = MFMA16(a1, wf, acc[1][nt]);
    }
  }

#pragma unroll
  for (int mt = 0; mt < 2; ++mt) {
    const int rowbase = tileM + wave * 32 + mt * 16 + quad * 4;  // C/D row = quad*4+reg
    const int b = rowbase >> 12, s = rowbase & 4095;
    const int g = s >> 5;
    if (which == 0) {
      // Q: [bh][s][64], scaled into log2 domain
#pragma unroll
      for (int nt = 0; nt < 8; ++nt) {
        const int col = tileN + nt * 16 + l15;
        const int h = col >> 6, d = col & 63;
        const float bc = bias[col];
#pragma unroll
        for (int r = 0; r < 4; ++r) {
          const int row = rowbase + r;
          const int ss = row & 4095;
          Qh[(size_t)((b * 8 + h) * 4096 + ss) * 64 + d] = f2bf((acc[mt][nt][r] + bc) * QSCALE);
        }
      }
    } else if (which == 1) {
      // K fragment chunks (lane-ordered: region*512 + quadk*128 + key15*8 + j)
      const int key = s & 31;
      const int tt = key >> 4;
      const int l15b = key & 15;                 // +r, stays <16
#pragma unroll
      for (int nt = 0; nt < 8; ++nt) {
        const int col = tileN + nt * 16 + l15;
        const int h = col >> 6, dd = col & 63;
        const int ks = dd >> 5, quadk = (dd >> 3) & 3, jj = dd & 7;
        const float bc = bias[col];
        const size_t base = ((size_t)(b * 8 + h) * 128 + g) * 4096 +
                            (size_t)(tt * 2 + ks) * 512 + (size_t)quadk * 128 + jj;
#pragma unroll
        for (int r = 0; r < 4; ++r)
          KV[base + (size_t)(l15b + r) * 8] = f2bf(acc[mt][nt][r] + bc);
      }
    } else {
      // V fragment chunks (lane-ordered: 2048 + dt*512 + quadv*128 + d15*8 + j)
      const int p32 = s & 31;                    // multiple of 4
      const int l0 = ((p32 & 15) >> 2) * 8 + (p32 >> 4) * 4;
      const int quadv = l0 >> 3, jv = l0 & 7;    // jv in {0,4}
#pragma unroll
      for (int nt = 0; nt < 8; ++nt) {
        const int col = tileN + nt * 16 + l15;
        const int h = col >> 6, dd = col & 63;
        const int dt = dd >> 4, l15v = dd & 15;
        const float bc = bias[col];
        shortx4 p;
        p.x = f2bf(acc[mt][nt][0] + bc);
        p.y = f2bf(acc[mt][nt][1] + bc);
        p.z = f2bf(acc[mt][nt][2] + bc);
        p.w = f2bf(acc[mt][nt][3] + bc);
        *(shortx4*)(KV + ((size_t)(b * 8 + h) * 128 + g) * 4096 + 2048 +
                    (size_t)dt * 512 + (size_t)quadv * 128 + (size_t)l15v * 8 + jv) = p;
      }
    }
  }
}

// ---------------------------------------------------------------------------
// Output projection: ctx bf16 [8192,512] x Wo^T + bo -> fp32 out. 128x128.
// ---------------------------------------------------------------------------
__global__ __launch_bounds__(256) void proj_o_kernel(
    const short* __restrict__ A, const short* __restrict__ W,
    const float* __restrict__ bias, float* __restrict__ out) {
  __shared__ __align__(16) short sA[2][4096];
  __shared__ __align__(16) short sB[2][4096];

  const int K = 512;
  const int tid = threadIdx.x;
  const int lane = tid & 63;
  const int wave = tid >> 6;
  const int l15 = lane & 15;
  const int quad = lane >> 4;
  const int tileM = blockIdx.x * 128;
  const int tileN = blockIdx.y * 128;

  const int srow = tid >> 2;
  const int fr = (srow ^ (srow >> 2)) & 3;
  const int sq = ((tid & 3) ^ fr) * 8;
  const short* As0 = A + (size_t)(tileM + srow) * K + sq;
  const short* As1 = As0 + (size_t)64 * K;
  const short* Bs0 = W + (size_t)(tileN + srow) * K + sq;
  const short* Bs1 = Bs0 + (size_t)64 * K;
  const int ldw = wave * 512;

  const int fl = (l15 ^ (l15 >> 2)) & 3;
  const int qsw = (quad ^ fl) * 8;
  const int ra0 = (wave * 32 + l15) * 32 + qsw;
  const int ra1 = ra0 + 512;
  const int rb0 = l15 * 32 + qsw;

  floatx4 acc[2][8];
#pragma unroll
  for (int mt = 0; mt < 2; ++mt)
#pragma unroll
    for (int nt = 0; nt < 8; ++nt) acc[mt][nt] = (floatx4){0.f, 0.f, 0.f, 0.f};

  stage16(As0, &sA[0][ldw]);
  stage16(As1, &sA[0][2048 + ldw]);
  stage16(Bs0, &sB[0][ldw]);
  stage16(Bs1, &sB[0][2048 + ldw]);

#pragma unroll 2
  for (int t = 0; t < 16; ++t) {
    __syncthreads();
    if (t != 15) {
      const int kk = (t + 1) * 32;
      short* a_ld = &sA[(t + 1) & 1][ldw];
      short* b_ld = &sB[(t + 1) & 1][ldw];
      stage16(As0 + kk, a_ld);
      stage16(As1 + kk, a_ld + 2048);
      stage16(Bs0 + kk, b_ld);
      stage16(Bs1 + kk, b_ld + 2048);
    }
    const short* sa = sA[t & 1];
    const short* sb = sB[t & 1];
    bf16x8 a0 = *(const bf16x8*)&sa[ra0];
    bf16x8 a1 = *(const bf16x8*)&sa[ra1];
#pragma unroll
    for (int nt = 0; nt < 8; ++nt) {
      bf16x8 wf = *(const bf16x8*)&sb[rb0 + nt * 512];
      acc[0][nt] = MFMA16(a0, wf, acc[0][nt]);
      acc[1][nt] = MFMA16(a1, wf, acc[1][nt]);
    }
  }

#pragma unroll
  for (int mt = 0; mt < 2; ++mt) {
    const int rowbase = tileM + wave * 32 + mt * 16 + quad * 4;
#pragma unroll
    for (int nt = 0; nt < 8; ++nt) {
      const int col = tileN + nt * 16 + l15;
      const float bc = bias[col];
#pragma unroll
      for (int r = 0; r < 4; ++r) out[(size_t)(rowbase + r) * 512 + col] = acc[mt][nt][r] + bc;
    }
  }
}

// ---------------------------------------------------------------------------
// Flash attention: 16 waves, 4-way key split. Wave = (qg = wave&3: 32 qrows)
// x (ks = wave>>2: key groups 4i+ks). 32 iters; per iter ONE barrier, stage
// next 32KB group-quad (2 stage16/thread), compute own group from LDS.
// No-max fixed-base softmax => quarter partials (o,l) combine linearly at
// the end through sKV reused as float scratch (2 rounds) + comb_l.
// LDS = 64KB sKV + 6KB comb_l => 2 blocks/CU x 16 waves = 8 waves/SIMD
// (launch_bounds(1024,8) locks VGPR <= 64).
// ---------------------------------------------------------------------------
__global__ __launch_bounds__(1024, 8) void flash_kernel(
    const short* __restrict__ Qh, const short* __restrict__ KV,
    short* __restrict__ ctx) {
  __shared__ __align__(16) short sKV[2][16384];   // 2 bufs x 4 groups x 8KB
  __shared__ float comb_l[3][4][64][2];           // quarter rowsums

  const int id = blockIdx.x;          // 0..511
  const int xcd = id & 7;
  const int j = id >> 3;              // 0..63
  const int bh = xcd + ((j >> 5) << 3);
  const int qtile = j & 31;

  const int tid = threadIdx.x;
  const int wave = tid >> 6;          // 0..15
  const int lane = tid & 63;
  const int l15 = lane & 15;
  const int quad = lane >> 4;
  const int qg = wave & 3;            // q-row group within block
  const int ks = wave >> 2;           // key quarter 0..3
  const int qrow0 = qtile * 128 + qg * 32;

  // Q B-frags: B[k=d=quad*8+i+32kslice][n=qrow=l15]
  bf16x8 qf[2][2];
#pragma unroll
  for (int nt = 0; nt < 2; ++nt) {
    const short* Qb = Qh + (size_t)(bh * 4096 + qrow0 + nt * 16 + l15) * 64 + quad * 8;
    qf[nt][0] = *(const bf16x8*)(Qb);
    qf[nt][1] = *(const bf16x8*)(Qb + 32);
  }

  // ones A-fragment (bf16 1.0 = 0x3F80) for MFMA row-sums
  bf16x8 ones;
  {
    union { short s[8]; bf16x8 v; } u;
#pragma unroll
    for (int i = 0; i < 8; ++i) u.s[i] = (short)0x3F80;
    ones = u.v;
  }

  const short* KVb = KV + (size_t)bh * (128 * 4096);
  const short* sg = KVb + wave * 1024 + lane * 8;   // staging src (wave's 2KB)
  const int ldw = wave * 1024;                      // wave-uniform LDS dest (shorts)

  const floatx4 FZ = (floatx4){0.f, 0.f, 0.f, 0.f};
  floatx4 o[2][4];
  floatx4 lacc[2];
#pragma unroll
  for (int nt = 0; nt < 2; ++nt) {
    lacc[nt] = FZ;
#pragma unroll
    for (int dt = 0; dt < 4; ++dt) o[nt][dt] = FZ;
  }

  // prologue: stage group-quad 0 (32KB = 16 waves x 2KB)
  stage16(sg, &sKV[0][ldw]);
  stage16(sg + 512, &sKV[0][ldw + 512]);

#define COMPUTE(S) do {                                                         \
    bf16x8 ka[2][2], vf[4];                                                     \
    ka[0][0] = *(const bf16x8*)&(S)[av];                                        \
    ka[0][1] = *(const bf16x8*)&(S)[av + 512];                                  \
    ka[1][0] = *(const bf16x8*)&(S)[av + 1024];                                 \
    ka[1][1] = *(const bf16x8*)&(S)[av + 1536];                                 \
    vf[0] = *(const bf16x8*)&(S)[av + 2048];                                    \
    vf[1] = *(const bf16x8*)&(S)[av + 2560];                                    \
    vf[2] = *(const bf16x8*)&(S)[av + 3072];                                    \
    vf[3] = *(const bf16x8*)&(S)[av + 3584];                                    \
    floatx4 st[2][2];                                                           \
    _Pragma("unroll")                                                           \
    for (int nt = 0; nt < 2; ++nt)                                              \
      _Pragma("unroll")                                                         \
      for (int t = 0; t < 2; ++t)                                               \
        st[nt][t] = MFMA16(ka[t][1], qf[nt][1], MFMA16(ka[t][0], qf[nt][0], FZ)); \
    bf16x8 pb[2];                                                               \
    _Pragma("unroll")                                                           \
    for (int nt = 0; nt < 2; ++nt) {                                            \
      float p[8];                                                               \
      _Pragma("unroll")                                                         \
      for (int t = 0; t < 2; ++t)                                               \
        _Pragma("unroll")                                                       \
        for (int r = 0; r < 4; ++r) p[t * 4 + r] = __builtin_amdgcn_exp2f(st[nt][t][r]); \
      union { __hip_bfloat162 h2[4]; bf16x8 v8; } u;                            \
      u.h2[0] = __float22bfloat162_rn(float2{p[0], p[1]});                      \
      u.h2[1] = __float22bfloat162_rn(float2{p[2], p[3]});                      \
      u.h2[2] = __float22bfloat162_rn(float2{p[4], p[5]});                      \
      u.h2[3] = __float22bfloat162_rn(float2{p[6], p[7]});                      \
      pb[nt] = u.v8;                                                            \
    }                                                                           \
    _Pragma("unroll")                                                           \
    for (int nt = 0; nt < 2; ++nt) {                                            \
      lacc[nt] = MFMA16(ones, pb[nt], lacc[nt]);                                \
      _Pragma("unroll")                                                         \
      for (int dt = 0; dt < 4; ++dt)                                            \
        o[nt][dt] = MFMA16(vf[dt], pb[nt], o[nt][dt]);                          \
    }                                                                           \
  } while (0)

  const int av = lane * 8;            // lane-ordered chunk address (conflict-free)

  for (int it = 0; it < 32; ++it) {
    __syncthreads();   // drains this wave's staging (vmcnt) + block-wide sync

    if (it != 31) {    // stage next group-quad into the other 32KB buffer
      const short* gs = sg + (size_t)(it + 1) * 16384;
      short* ld = &sKV[(it + 1) & 1][ldw];
      stage16(gs, ld);
      stage16(gs + 512, ld + 512);
    }

    const short* S = &sKV[it & 1][ks << 12];  // quarter ks: group 4*it+ks
    COMPUTE(S);
  }
#undef COMPUTE

  // ---- combine quarters (2 rounds through sKV-as-float + comb_l) ----
  __syncthreads();
  float* cb = (float*)sKV;                        // 16384 floats (64KB)
  const int slot = (qg * 64 + lane) * 32;
  const int rot = lane & 7;                       // chunk-XOR vs bank conflicts

  if (ks == 1 || ks == 3) {
    float* dst = cb + (ks == 3 ? 8192 : 0) + slot;
#pragma unroll
    for (int nt = 0; nt < 2; ++nt)
#pragma unroll
      for (int dt = 0; dt < 4; ++dt) {
        const int c = nt * 4 + dt;
        *(floatx4*)(dst + ((c ^ rot) & 7) * 4) = o[nt][dt];
      }
  }
  if (ks) {
    comb_l[ks - 1][qg][lane][0] = lacc[0][0];
    comb_l[ks - 1][qg][lane][1] = lacc[1][0];
  }
  __syncthreads();
  if (ks == 0 || ks == 2) {                       // 0 += quarter1, 2 += quarter3
    const float* src = cb + (ks == 2 ? 8192 : 0) + slot;
#pragma unroll
    for (int nt = 0; nt < 2; ++nt)
#pragma unroll
      for (int dt = 0; dt < 4; ++dt) {
        const int c = nt * 4 + dt;
        o[nt][dt] += *(const floatx4*)(src + ((c ^ rot) & 7) * 4);
      }
  }
  __syncthreads();
  if (ks == 2) {                                  // publish (2+3) partial
    float* dst = cb + slot;
#pragma unroll
    for (int nt = 0; nt < 2; ++nt)
#pragma unroll
      for (int dt = 0; dt < 4; ++dt) {
        const int c = nt * 4 + dt;
        *(floatx4*)(dst + ((c ^ rot) & 7) * 4) = o[nt][dt];
      }
  }
  __syncthreads();
  if (ks == 0) {                                  // finish: += (2+3), write ctx
    const float* src = cb + slot;
#pragma unroll
    for (int nt = 0; nt < 2; ++nt)
#pragma unroll
      for (int dt = 0; dt < 4; ++dt) {
        const int c = nt * 4 + dt;
        o[nt][dt] += *(const floatx4*)(src + ((c ^ rot) & 7) * 4);
      }
    const int b = bh >> 3, h = bh & 7;
#pragma unroll
    for (int nt = 0; nt < 2; ++nt) {
      const float lt = lacc[nt][0] + comb_l[0][qg][lane][nt] +
                       comb_l[1][qg][lane][nt] + comb_l[2][qg][lane][nt];
      const float inv = 1.0f / lt;
      const int row = qrow0 + nt * 16 + l15;
      short* cp = ctx + (size_t)(b * 4096 + row) * 512 + h * 64 + quad * 4;
#pragma unroll
      for (int dt = 0; dt < 4; ++dt) {
        union { __hip_bfloat162 h2[2]; shortx4 s4; } u;
        u.h2[0] = __float22bfloat162_rn(float2{o[nt][dt][0] * inv, o[nt][dt][1] * inv});
        u.h2[1] = __float22bfloat162_rn(float2{o[nt][dt][2] * inv, o[nt][dt][3] * inv});
        *(shortx4*)(cp + dt * 16) = u.s4;
      }
    }
  }
}

// ---------------------------------------------------------------------------
extern "C" void kernel_launch(void* const* d_in, const int* in_sizes, int n_in,
                              void* d_out, int out_size, void* d_ws, size_t ws_size,
                              hipStream_t stream) {
  const float* q  = (const float*)d_in[0];
  const float* k  = (const float*)d_in[1];
  const float* v  = (const float*)d_in[2];
  const float* Wq = (const float*)d_in[3];
  const float* bq = (const float*)d_in[4];
  const float* Wk = (const float*)d_in[5];
  const float* bk = (const float*)d_in[6];
  const float* Wv = (const float*)d_in[7];
  const float* bv = (const float*)d_in[8];
  const float* Wo = (const float*)d_in[9];
  const float* bo = (const float*)d_in[10];

  const int XN = 2 * 4096 * 512;
  const int WN = 512 * 512;

  short* ws  = (short*)d_ws;
  short* xqb = ws;                       // q/k/v bf16 (contiguous)
  short* xkb = ws + (size_t)XN;
  short* xvb = ws + (size_t)2 * XN;
  short* wqb = ws + (size_t)3 * XN;      // weights bf16 (contiguous)
  short* wkb = wqb + WN;
  short* wvb = wkb + WN;
  short* wob = wvb + WN;
  short* Qh  = wob + WN;
  short* KVf = Qh + (size_t)XN;          // fragment-ordered K+V: 2*XN shorts
  short* ctx = xqb;                      // xq dead after projections

  const int A4 = XN / 4, W4 = WN / 4;
  cvt_all_kernel<<<(3 * A4 + 4 * W4) / 256, 256, 0, stream>>>(
      q, k, v, Wq, Wk, Wv, Wo, xqb, wqb);

  dim3 pg(64, 4, 3);
  proj3_kernel<<<pg, 256, 0, stream>>>(xqb, xkb, xvb, wqb, wkb, wvb,
                                       bq, bk, bv, Qh, KVf);

  flash_kernel<<<512, 1024, 0, stream>>>(Qh, KVf, ctx);

  dim3 og(64, 4);
  proj_o_kernel<<<og, 256, 0, stream>>>(ctx, wob, bo, (float*)d_out);
}

// Round 3
// 215.069 us; speedup vs baseline: 2.9942x; 2.9942x over previous
//
#include <hip/hip_runtime.h>
#include <hip/hip_bf16.h>
#include <stdint.h>

// ---------------------------------------------------------------------------
// MHA: B=2, S=4096, D=512, H=8, dk=64.
// R12:
//  * flash: back to R10 geometry (512 thr = 8 waves, 4 qg x 2 key-half,
//    52-VGPR class, NO min-waves bound — R11's (1024,8) bound spilled the
//    accumulators: 2.3GB scratch traffic). Upgrades, all occupancy-safe:
//      - triple-buffered staging (3 x 16KB pairs) with counted
//        `s_waitcnt vmcnt(2) lgkmcnt(0)` + raw s_barrier: pair it+1 stays
//        in flight across the barrier (never vmcnt(0) in the loop).
//      - combine scratch aliases sKV (loop done) => LDS 67.5KB -> 48KB.
//      - s_setprio(1) around the MFMA/exp2 chain (T5).
//  * proj3/proj_o: R11's 128x128 staged GEMM (verified). cvt_all merged.
// ---------------------------------------------------------------------------

typedef float  floatx4 __attribute__((ext_vector_type(4)));
typedef __bf16 bf16x8  __attribute__((ext_vector_type(8)));
typedef short  shortx4 __attribute__((ext_vector_type(4)));

#define MFMA16(a, b, c) __builtin_amdgcn_mfma_f32_16x16x32_bf16((a), (b), (c), 0, 0, 0)

// folded into Q projection: (1/sqrt(64)) * log2(e)  -> scores in log2 domain
#define QSCALE 0.1803368801111244f

__device__ __forceinline__ short f2bf(float f) {   // RNE
  union { float f; uint32_t u; } a; a.f = f;
  uint32_t u = a.u;
  u += 0x7fffu + ((u >> 16) & 1u);
  return (short)(u >> 16);
}

// async global->LDS, 16B per lane; lds dest = wave-uniform base + lane*16
__device__ __forceinline__ void stage16(const short* g, short* l) {
  __builtin_amdgcn_global_load_lds(
      (const __attribute__((address_space(1))) void*)g,
      (__attribute__((address_space(3))) void*)l, 16, 0, 0);
}

// ---------------------------------------------------------------------------
// fp32 -> bf16 for all 7 tensors in one flat grid.
// act: q,k,v (A4 float4-units each, A4 = 2^20); wts: Wq,Wk,Wv,Wo (W4 = 2^16).
// ---------------------------------------------------------------------------
__global__ __launch_bounds__(256) void cvt_all_kernel(
    const float* __restrict__ q, const float* __restrict__ k, const float* __restrict__ v,
    const float* __restrict__ Wq, const float* __restrict__ Wk,
    const float* __restrict__ Wv, const float* __restrict__ Wo,
    short* __restrict__ act, short* __restrict__ wts) {
  const int A4 = (2 * 4096 * 512) / 4;   // 1048576 = 2^20
  const int W4 = (512 * 512) / 4;        // 65536   = 2^16
  const int i = blockIdx.x * 256 + threadIdx.x;
  const float* in;
  short* out;
  int j;
  if (i < 3 * A4) {
    const int which = i >> 20;           // / A4
    j = i - which * A4;
    in = which == 0 ? q : which == 1 ? k : v;
    out = act + (size_t)which * (size_t)A4 * 4;
  } else {
    const int t = i - 3 * A4;
    const int which = t >> 16;           // / W4
    j = t - which * W4;
    in = which == 0 ? Wq : which == 1 ? Wk : which == 2 ? Wv : Wo;
    out = wts + (size_t)which * (size_t)W4 * 4;
  }
  float4 f = reinterpret_cast<const float4*>(in)[j];
  shortx4 s;
  s.x = f2bf(f.x); s.y = f2bf(f.y); s.z = f2bf(f.z); s.w = f2bf(f.w);
  reinterpret_cast<shortx4*>(out)[j] = s;
}

// ---------------------------------------------------------------------------
// Fused Q/K/V projection. blockIdx.z picks tensor. A[8192,512] x W[512,512]^T.
// 128x128 tile, BK=32, double-buffered LDS (global_load_lds, 1 barrier/iter).
// LDS layout: row-major [rows][32] with k-chunk XOR swizzle:
//   cell(row, q) stored at chunk q ^ ((row ^ (row>>2)) & 3)   (16B chunks)
// Staging pre-swizzles the GLOBAL source k-offset (LDS dest stays linear);
// fragment ds_read applies the same XOR (depends only on l15 — invariant in
// mt/nt/wave since those shift row by multiples of 4).
// Wave = 32 rows x 128 cols: 16 MFMA / 10 ds_read_b128 per k-step.
// Epilogues identical to R9/R10 (Q scaled log2-domain; K/V fragment-ordered).
// ---------------------------------------------------------------------------
__global__ __launch_bounds__(256) void proj3_kernel(
    const short* __restrict__ xq, const short* __restrict__ xk, const short* __restrict__ xv,
    const short* __restrict__ wq, const short* __restrict__ wk, const short* __restrict__ wv,
    const float* __restrict__ bq, const float* __restrict__ bk, const float* __restrict__ bv,
    short* __restrict__ Qh, short* __restrict__ KV) {
  const int which = blockIdx.z;
  const short* A = which == 0 ? xq : which == 1 ? xk : xv;
  const short* W = which == 0 ? wq : which == 1 ? wk : wv;
  const float* bias = which == 0 ? bq : which == 1 ? bk : bv;

  __shared__ __align__(16) short sA[2][4096];   // [128][32] swizzled
  __shared__ __align__(16) short sB[2][4096];   // [128][32] swizzled

  const int K = 512;
  const int tid = threadIdx.x;
  const int lane = tid & 63;
  const int wave = tid >> 6;
  const int l15 = lane & 15;
  const int quad = lane >> 4;
  const int tileM = blockIdx.x * 128;
  const int tileN = blockIdx.y * 128;

  // staging: thread t covers LDS 16B chunk (row = t>>2 [+64], chunk = t&3);
  // source k-chunk pre-swizzled so LDS holds cell(row, (t&3)^fr) at slot t&3.
  const int srow = tid >> 2;                       // 0..63
  const int fr = (srow ^ (srow >> 2)) & 3;         // same for srow+64
  const int sq = ((tid & 3) ^ fr) * 8;
  const short* As0 = A + (size_t)(tileM + srow) * K + sq;        // rows 0..63
  const short* As1 = As0 + (size_t)64 * K;                       // rows 64..127
  const short* Bs0 = W + (size_t)(tileN + srow) * K + sq;
  const short* Bs1 = Bs0 + (size_t)64 * K;
  const int ldw = wave * 512;                      // wave-uniform LDS slice (shorts)

  // fragment reads: swizzled chunk = quad ^ f(l15)
  const int fl = (l15 ^ (l15 >> 2)) & 3;
  const int qsw = (quad ^ fl) * 8;
  const int ra0 = (wave * 32 + l15) * 32 + qsw;    // A frag mt=0
  const int ra1 = ra0 + 512;                       // mt=1 (+16 rows)
  const int rb0 = l15 * 32 + qsw;                  // B frag (+ nt*512)

  floatx4 acc[2][8];
#pragma unroll
  for (int mt = 0; mt < 2; ++mt)
#pragma unroll
    for (int nt = 0; nt < 8; ++nt) acc[mt][nt] = (floatx4){0.f, 0.f, 0.f, 0.f};

  // prologue: stage k-slice 0 into buffer 0
  stage16(As0, &sA[0][ldw]);
  stage16(As1, &sA[0][2048 + ldw]);
  stage16(Bs0, &sB[0][ldw]);
  stage16(Bs1, &sB[0][2048 + ldw]);

#pragma unroll 2
  for (int t = 0; t < 16; ++t) {
    __syncthreads();                 // drains own stage vmcnt + block sync
    if (t != 15) {                   // stage next slice into other buffer
      const int kk = (t + 1) * 32;
      short* a_ld = &sA[(t + 1) & 1][ldw];
      short* b_ld = &sB[(t + 1) & 1][ldw];
      stage16(As0 + kk, a_ld);
      stage16(As1 + kk, a_ld + 2048);
      stage16(Bs0 + kk, b_ld);
      stage16(Bs1 + kk, b_ld + 2048);
    }
    const short* sa = sA[t & 1];
    const short* sb = sB[t & 1];
    bf16x8 a0 = *(const bf16x8*)&sa[ra0];
    bf16x8 a1 = *(const bf16x8*)&sa[ra1];
#pragma unroll
    for (int nt = 0; nt < 8; ++nt) {
      bf16x8 wf = *(const bf16x8*)&sb[rb0 + nt * 512];
      acc[0][nt] = MFMA16(a0, wf, acc[0][nt]);
      acc[1][nt] = MFMA16(a1, wf, acc[1][nt]);
    }
  }

#pragma unroll
  for (int mt = 0; mt < 2; ++mt) {
    const int rowbase = tileM + wave * 32 + mt * 16 + quad * 4;  // C/D row = quad*4+reg
    const int b = rowbase >> 12, s = rowbase & 4095;
    const int g = s >> 5;
    if (which == 0) {
      // Q: [bh][s][64], scaled into log2 domain
#pragma unroll
      for (int nt = 0; nt < 8; ++nt) {
        const int col = tileN + nt * 16 + l15;
        const int h = col >> 6, d = col & 63;
        const float bc = bias[col];
#pragma unroll
        for (int r = 0; r < 4; ++r) {
          const int row = rowbase + r;
          const int ss = row & 4095;
          Qh[(size_t)((b * 8 + h) * 4096 + ss) * 64 + d] = f2bf((acc[mt][nt][r] + bc) * QSCALE);
        }
      }
    } else if (which == 1) {
      // K fragment chunks (lane-ordered: region*512 + quadk*128 + key15*8 + j)
      const int key = s & 31;
      const int tt = key >> 4;
      const int l15b = key & 15;                 // +r, stays <16
#pragma unroll
      for (int nt = 0; nt < 8; ++nt) {
        const int col = tileN + nt * 16 + l15;
        const int h = col >> 6, dd = col & 63;
        const int ks = dd >> 5, quadk = (dd >> 3) & 3, jj = dd & 7;
        const float bc = bias[col];
        const size_t base = ((size_t)(b * 8 + h) * 128 + g) * 4096 +
                            (size_t)(tt * 2 + ks) * 512 + (size_t)quadk * 128 + jj;
#pragma unroll
        for (int r = 0; r < 4; ++r)
          KV[base + (size_t)(l15b + r) * 8] = f2bf(acc[mt][nt][r] + bc);
      }
    } else {
      // V fragment chunks (lane-ordered: 2048 + dt*512 + quadv*128 + d15*8 + j)
      const int p32 = s & 31;                    // multiple of 4
      const int l0 = ((p32 & 15) >> 2) * 8 + (p32 >> 4) * 4;
      const int quadv = l0 >> 3, jv = l0 & 7;    // jv in {0,4}
#pragma unroll
      for (int nt = 0; nt < 8; ++nt) {
        const int col = tileN + nt * 16 + l15;
        const int h = col >> 6, dd = col & 63;
        const int dt = dd >> 4, l15v = dd & 15;
        const float bc = bias[col];
        shortx4 p;
        p.x = f2bf(acc[mt][nt][0] + bc);
        p.y = f2bf(acc[mt][nt][1] + bc);
        p.z = f2bf(acc[mt][nt][2] + bc);
        p.w = f2bf(acc[mt][nt][3] + bc);
        *(shortx4*)(KV + ((size_t)(b * 8 + h) * 128 + g) * 4096 + 2048 +
                    (size_t)dt * 512 + (size_t)quadv * 128 + (size_t)l15v * 8 + jv) = p;
      }
    }
  }
}

// ---------------------------------------------------------------------------
// Output projection: ctx bf16 [8192,512] x Wo^T + bo -> fp32 out. 128x128.
// ---------------------------------------------------------------------------
__global__ __launch_bounds__(256) void proj_o_kernel(
    const short* __restrict__ A, const short* __restrict__ W,
    const float* __restrict__ bias, float* __restrict__ out) {
  __shared__ __align__(16) short sA[2][4096];
  __shared__ __align__(16) short sB[2][4096];

  const int K = 512;
  const int tid = threadIdx.x;
  const int lane = tid & 63;
  const int wave = tid >> 6;
  const int l15 = lane & 15;
  const int quad = lane >> 4;
  const int tileM = blockIdx.x * 128;
  const int tileN = blockIdx.y * 128;

  const int srow = tid >> 2;
  const int fr = (srow ^ (srow >> 2)) & 3;
  const int sq = ((tid & 3) ^ fr) * 8;
  const short* As0 = A + (size_t)(tileM + srow) * K + sq;
  const short* As1 = As0 + (size_t)64 * K;
  const short* Bs0 = W + (size_t)(tileN + srow) * K + sq;
  const short* Bs1 = Bs0 + (size_t)64 * K;
  const int ldw = wave * 512;

  const int fl = (l15 ^ (l15 >> 2)) & 3;
  const int qsw = (quad ^ fl) * 8;
  const int ra0 = (wave * 32 + l15) * 32 + qsw;
  const int ra1 = ra0 + 512;
  const int rb0 = l15 * 32 + qsw;

  floatx4 acc[2][8];
#pragma unroll
  for (int mt = 0; mt < 2; ++mt)
#pragma unroll
    for (int nt = 0; nt < 8; ++nt) acc[mt][nt] = (floatx4){0.f, 0.f, 0.f, 0.f};

  stage16(As0, &sA[0][ldw]);
  stage16(As1, &sA[0][2048 + ldw]);
  stage16(Bs0, &sB[0][ldw]);
  stage16(Bs1, &sB[0][2048 + ldw]);

#pragma unroll 2
  for (int t = 0; t < 16; ++t) {
    __syncthreads();
    if (t != 15) {
      const int kk = (t + 1) * 32;
      short* a_ld = &sA[(t + 1) & 1][ldw];
      short* b_ld = &sB[(t + 1) & 1][ldw];
      stage16(As0 + kk, a_ld);
      stage16(As1 + kk, a_ld + 2048);
      stage16(Bs0 + kk, b_ld);
      stage16(Bs1 + kk, b_ld + 2048);
    }
    const short* sa = sA[t & 1];
    const short* sb = sB[t & 1];
    bf16x8 a0 = *(const bf16x8*)&sa[ra0];
    bf16x8 a1 = *(const bf16x8*)&sa[ra1];
#pragma unroll
    for (int nt = 0; nt < 8; ++nt) {
      bf16x8 wf = *(const bf16x8*)&sb[rb0 + nt * 512];
      acc[0][nt] = MFMA16(a0, wf, acc[0][nt]);
      acc[1][nt] = MFMA16(a1, wf, acc[1][nt]);
    }
  }

#pragma unroll
  for (int mt = 0; mt < 2; ++mt) {
    const int rowbase = tileM + wave * 32 + mt * 16 + quad * 4;
#pragma unroll
    for (int nt = 0; nt < 8; ++nt) {
      const int col = tileN + nt * 16 + l15;
      const float bc = bias[col];
#pragma unroll
      for (int r = 0; r < 4; ++r) out[(size_t)(rowbase + r) * 512 + col] = acc[mt][nt][r] + bc;
    }
  }
}

// ---------------------------------------------------------------------------
// Flash attention: R10 geometry (8 waves: 4 qg x 2 key-half), triple-buffered
// staging with counted vmcnt. Per iter: s_waitcnt vmcnt(2) lgkmcnt(0) (pair
// `it` retired, pair `it+1` stays in flight ACROSS the barrier) -> s_barrier
// -> stage pair it+2 into the rotating 3rd buffer -> setprio(1) COMPUTE
// setprio(0). lgkmcnt(0) before the barrier guarantees this wave's prior
// ds_reads finished before any wave restages that buffer (rule-#18 hazard).
// Combine scratch aliases sKV after the loop => LDS 48KB total.
// ---------------------------------------------------------------------------
__global__ __launch_bounds__(512) void flash_kernel(
    const short* __restrict__ Qh, const short* __restrict__ KV,
    short* __restrict__ ctx) {
  __shared__ __align__(16) short sKV[3][8192];   // 3 bufs x 16KB pairs (48KB)

  const int id = blockIdx.x;          // 0..511
  const int xcd = id & 7;
  const int j = id >> 3;              // 0..63
  const int bh = xcd + ((j >> 5) << 3);
  const int qtile = j & 31;

  const int tid = threadIdx.x;
  const int wave = tid >> 6;          // 0..7
  const int lane = tid & 63;
  const int l15 = lane & 15;
  const int quad = lane >> 4;
  const int wq = wave & 3;            // q-row group within block
  const int half = wave >> 2;         // key half: 0 -> group 2i, 1 -> 2i+1
  const int qrow0 = qtile * 128 + wq * 32;

  // Q B-frags: B[k=d=quad*8+i+32ks][n=qrow=l15]
  bf16x8 qf[2][2];
#pragma unroll
  for (int nt = 0; nt < 2; ++nt) {
    const short* Qb = Qh + (size_t)(bh * 4096 + qrow0 + nt * 16 + l15) * 64 + quad * 8;
    qf[nt][0] = *(const bf16x8*)(Qb);
    qf[nt][1] = *(const bf16x8*)(Qb + 32);
  }

  // ones A-fragment (bf16 1.0 = 0x3F80) for MFMA row-sums
  bf16x8 ones;
  {
    union { short s[8]; bf16x8 v; } u;
#pragma unroll
    for (int i = 0; i < 8; ++i) u.s[i] = (short)0x3F80;
    ones = u.v;
  }

  const short* KVb = KV + (size_t)bh * (128 * 4096);
  const short* sg = KVb + wave * 512 + lane * 8;    // staging src (wave slice)
  const int ldw = wave * 512;                       // wave-uniform LDS dest offset

  const floatx4 FZ = (floatx4){0.f, 0.f, 0.f, 0.f};
  floatx4 o[2][4];
  floatx4 lacc[2];
#pragma unroll
  for (int nt = 0; nt < 2; ++nt) {
    lacc[nt] = FZ;
#pragma unroll
    for (int dt = 0; dt < 4; ++dt) o[nt][dt] = FZ;
  }

  // prologue: stage pairs 0 and 1 (8 waves x 2 x 1KB = 16KB each)
  stage16(sg, &sKV[0][ldw]);
  stage16(sg + 4096, &sKV[0][ldw + 4096]);
  stage16(sg + 8192, &sKV[1][ldw]);
  stage16(sg + 12288, &sKV[1][ldw + 4096]);

#define COMPUTE(S) do {                                                         \
    bf16x8 ka[2][2], vf[4];                                                     \
    ka[0][0] = *(const bf16x8*)&(S)[av];                                        \
    ka[0][1] = *(const bf16x8*)&(S)[av + 512];                                  \
    ka[1][0] = *(const bf16x8*)&(S)[av + 1024];                                 \
    ka[1][1] = *(const bf16x8*)&(S)[av + 1536];                                 \
    vf[0] = *(const bf16x8*)&(S)[av + 2048];                                    \
    vf[1] = *(const bf16x8*)&(S)[av + 2560];                                    \
    vf[2] = *(const bf16x8*)&(S)[av + 3072];                                    \
    vf[3] = *(const bf16x8*)&(S)[av + 3584];                                    \
    floatx4 st[2][2];                                                           \
    _Pragma("unroll")                                                           \
    for (int nt = 0; nt < 2; ++nt)                                              \
      _Pragma("unroll")                                                         \
      for (int t = 0; t < 2; ++t)                                               \
        st[nt][t] = MFMA16(ka[t][1], qf[nt][1], MFMA16(ka[t][0], qf[nt][0], FZ)); \
    bf16x8 pb[2];                                                               \
    _Pragma("unroll")                                                           \
    for (int nt = 0; nt < 2; ++nt) {                                            \
      float p[8];                                                               \
      _Pragma("unroll")                                                         \
      for (int t = 0; t < 2; ++t)                                               \
        _Pragma("unroll")                                                       \
        for (int r = 0; r < 4; ++r) p[t * 4 + r] = __builtin_amdgcn_exp2f(st[nt][t][r]); \
      union { __hip_bfloat162 h2[4]; bf16x8 v8; } u;                            \
      u.h2[0] = __float22bfloat162_rn(float2{p[0], p[1]});                      \
      u.h2[1] = __float22bfloat162_rn(float2{p[2], p[3]});                      \
      u.h2[2] = __float22bfloat162_rn(float2{p[4], p[5]});                      \
      u.h2[3] = __float22bfloat162_rn(float2{p[6], p[7]});                      \
      pb[nt] = u.v8;                                                            \
    }                                                                           \
    _Pragma("unroll")                                                           \
    for (int nt = 0; nt < 2; ++nt) {                                            \
      lacc[nt] = MFMA16(ones, pb[nt], lacc[nt]);                                \
      _Pragma("unroll")                                                         \
      for (int dt = 0; dt < 4; ++dt)                                            \
        o[nt][dt] = MFMA16(vf[dt], pb[nt], o[nt][dt]);                          \
    }                                                                           \
  } while (0)

  const int av = lane * 8;            // lane-ordered chunk address (conflict-free)

  short* p0 = sKV[0];
  short* p1 = sKV[1];
  short* p2 = sKV[2];

  for (int it = 0; it < 64; ++it) {
    // retire pair `it` (oldest 2 of this wave's stage ops); pair it+1 stays
    // in flight across the barrier. lgkmcnt(0): prior ds_reads all done
    // before any wave restages the buffer they targeted.
    if (it < 63) asm volatile("s_waitcnt vmcnt(2) lgkmcnt(0)" ::: "memory");
    else         asm volatile("s_waitcnt vmcnt(0) lgkmcnt(0)" ::: "memory");
    __builtin_amdgcn_s_barrier();

    if (it < 62) {   // stage pair it+2 into the buffer read at iter it-1
      const short* gs = sg + (size_t)(it + 2) * 8192;
      stage16(gs, p2 + ldw);
      stage16(gs + 4096, p2 + ldw + 4096);
    }

    __builtin_amdgcn_s_setprio(1);
    const short* S = p0 + (half << 12);  // half 0: group 2it; half 1: 2it+1
    COMPUTE(S);
    __builtin_amdgcn_s_setprio(0);

    short* t = p0; p0 = p1; p1 = p2; p2 = t;   // rotate buffers
  }
#undef COMPUTE

  // ---- combine halves through sKV-as-float scratch (loop done) ----
  __syncthreads();
  float* cb = (float*)sKV;             // 4 qg x 64 lanes x 34 floats = 34.8KB
  if (half) {
    float* c = cb + (size_t)(wq * 64 + lane) * 34;
#pragma unroll
    for (int nt = 0; nt < 2; ++nt) {
#pragma unroll
      for (int dt = 0; dt < 4; ++dt)
#pragma unroll
        for (int r = 0; r < 4; ++r) c[nt * 16 + dt * 4 + r] = o[nt][dt][r];
      c[32 + nt] = lacc[nt][0];
    }
  }
  __syncthreads();
  if (!half) {
    const float* c = cb + (size_t)(wq * 64 + lane) * 34;
    const int b = bh >> 3, h = bh & 7;
#pragma unroll
    for (int nt = 0; nt < 2; ++nt) {
      const float inv = 1.0f / (lacc[nt][0] + c[32 + nt]);
      const int row = qrow0 + nt * 16 + l15;
      short* cp = ctx + (size_t)(b * 4096 + row) * 512 + h * 64 + quad * 4;
#pragma unroll
      for (int dt = 0; dt < 4; ++dt) {
        union { __hip_bfloat162 h2[2]; shortx4 s4; } u;
        u.h2[0] = __float22bfloat162_rn(
            float2{(o[nt][dt][0] + c[nt * 16 + dt * 4 + 0]) * inv,
                   (o[nt][dt][1] + c[nt * 16 + dt * 4 + 1]) * inv});
        u.h2[1] = __float22bfloat162_rn(
            float2{(o[nt][dt][2] + c[nt * 16 + dt * 4 + 2]) * inv,
                   (o[nt][dt][3] + c[nt * 16 + dt * 4 + 3]) * inv});
        *(shortx4*)(cp + dt * 16) = u.s4;
      }
    }
  }
}

// ---------------------------------------------------------------------------
extern "C" void kernel_launch(void* const* d_in, const int* in_sizes, int n_in,
                              void* d_out, int out_size, void* d_ws, size_t ws_size,
                              hipStream_t stream) {
  const float* q  = (const float*)d_in[0];
  const float* k  = (const float*)d_in[1];
  const float* v  = (const float*)d_in[2];
  const float* Wq = (const float*)d_in[3];
  const float* bq = (const float*)d_in[4];
  const float* Wk = (const float*)d_in[5];
  const float* bk = (const float*)d_in[6];
  const float* Wv = (const float*)d_in[7];
  const float* bv = (const float*)d_in[8];
  const float* Wo = (const float*)d_in[9];
  const float* bo = (const float*)d_in[10];

  const int XN = 2 * 4096 * 512;
  const int WN = 512 * 512;

  short* ws  = (short*)d_ws;
  short* xqb = ws;                       // q/k/v bf16 (contiguous)
  short* xkb = ws + (size_t)XN;
  short* xvb = ws + (size_t)2 * XN;
  short* wqb = ws + (size_t)3 * XN;      // weights bf16 (contiguous)
  short* wkb = wqb + WN;
  short* wvb = wkb + WN;
  short* wob = wvb + WN;
  short* Qh  = wob + WN;
  short* KVf = Qh + (size_t)XN;          // fragment-ordered K+V: 2*XN shorts
  short* ctx = xqb;                      // xq dead after projections

  const int A4 = XN / 4, W4 = WN / 4;
  cvt_all_kernel<<<(3 * A4 + 4 * W4) / 256, 256, 0, stream>>>(
      q, k, v, Wq, Wk, Wv, Wo, xqb, wqb);

  dim3 pg(64, 4, 3);
  proj3_kernel<<<pg, 256, 0, stream>>>(xqb, xkb, xvb, wqb, wkb, wvb,
                                       bq, bk, bv, Qh, KVf);

  flash_kernel<<<512, 512, 0, stream>>>(Qh, KVf, ctx);

  dim3 og(64, 4);
  proj_o_kernel<<<og, 256, 0, stream>>>(ctx, wob, bo, (float*)d_out);
}